// Round 16
// baseline (1501.249 us; speedup 1.0000x reference)
//
#include <hip/hip_runtime.h>
#include <math.h>

#define T_LEN 1024
#define B_SZ  256
#define I_SZ  128
#define H_SZ  64
#define G_SZ  256   // 4*H

typedef float f32x8 __attribute__((ext_vector_type(8)));

__device__ __forceinline__ float fast_sigmoid(float x) {  // |x|<~15 safe
    float e = __expf(-x);
    return __builtin_amdgcn_rcpf(1.0f + e);
}
__device__ __forceinline__ float fast_tanh_b(float x) {   // |x|<~15 safe, branchless
    float e = __expf(-2.0f * x);
    return (1.0f - e) * __builtin_amdgcn_rcpf(1.0f + e);
}
__device__ __forceinline__ float fast_tanh(float x) {     // safe for any |x| (cell)
    float e = __expf(-2.0f * fabsf(x));
    float r = (1.0f - e) * __builtin_amdgcn_rcpf(1.0f + e);
    return copysignf(r, x);
}

#define LD8PIN(V, P)                                                        \
    {   float4 t0_ = *reinterpret_cast<const float4*>(P);                   \
        float4 t1_ = *reinterpret_cast<const float4*>((P) + 4);             \
        V = (f32x8){t0_.x, t0_.y, t0_.z, t0_.w, t1_.x, t1_.y, t1_.z, t1_.w};\
        asm volatile("" : "+v"(V)); }

// One readlane of h[k] feeds FOUR gate-row FMAs (i,f,g,o). K literal:
// readlane lane-index must be wave-uniform (R12 lesson).
#define DOT8(VI, VF, VG, VO, K)                                             \
    { _Pragma("unroll") for (int q_ = 0; q_ < 8; ++q_) {                    \
        unsigned s_ = __builtin_amdgcn_readlane(hu, (K) + q_);              \
        const float hv_ = __uint_as_float(s_);                              \
        ai = fmaf(hv_, VI[q_], ai);                                         \
        af = fmaf(hv_, VF[q_], af);                                         \
        ag = fmaf(hv_, VG[q_], ag);                                         \
        ao = fmaf(hv_, VO[q_], ao); } }

// LDS column swizzle for the GEMM tiles
__device__ __forceinline__ int swz(int c) { return c + 4 * (c >> 5); }

// GEMM staging: global -> regs (issued early, latency hidden under compute)
#define GLOAD(K0)                                                           \
    { _Pragma("unroll") for (int i_ = 0; i_ < 4; ++i_) {                    \
        const int mr_ = srow + 32 * i_;                                     \
        pa[i_] = *reinterpret_cast<const float4*>(                          \
            &xch[(size_t)(mt * 128 + mr_) * I_SZ + (K0) + skk]);            \
        pb[i_] = *reinterpret_cast<const float4*>(                          \
            &W_ih[(size_t)(nt * 128 + mr_) * I_SZ + (K0) + skk]); } }

// GEMM staging: regs -> LDS (after compute; one barrier per stage)
#define SWRITE(BUF)                                                         \
    { _Pragma("unroll") for (int i_ = 0; i_ < 4; ++i_) {                    \
        const int mr_ = srow + 32 * i_; const int sm_ = swz(mr_);           \
        as[BUF][skk + 0][sm_] = pa[i_].x; as[BUF][skk + 1][sm_] = pa[i_].y; \
        as[BUF][skk + 2][sm_] = pa[i_].z; as[BUF][skk + 3][sm_] = pa[i_].w; \
        bs[BUF][skk + 0][sm_] = pb[i_].x; bs[BUF][skk + 1][sm_] = pb[i_].y; \
        bs[BUF][skk + 2][sm_] = pb[i_].z; bs[BUF][skk + 3][sm_] = pb[i_].w; } }

// ---------------------------------------------------------------------------
// XG GEMM, double-buffered (unchanged, R13: ~190us)
// ---------------------------------------------------------------------------
__global__ __launch_bounds__(256, 2) void xg_gemm(
    const float* __restrict__ xch,    // [Mc,128] chunk of x
    const float* __restrict__ W_ih,   // [256,128]
    const float* __restrict__ bias,   // [256]
    float* __restrict__ XG)           // [Mc,256]
{
    const int tid = threadIdx.x;
    const int tx  = tid & 15;
    const int ty  = tid >> 4;
    const int mt  = blockIdx.x;
    const int nt  = blockIdx.y;

    __shared__ __align__(16) float as[2][32][140];   // 35.8 KB
    __shared__ __align__(16) float bs[2][32][140];   // 35.8 KB

    const int n0 = nt * 128 + tx * 8;
    float4 bia = *reinterpret_cast<const float4*>(&bias[n0]);
    float4 bib = *reinterpret_cast<const float4*>(&bias[n0 + 4]);

    float acc[8][8];
#pragma unroll
    for (int r = 0; r < 8; ++r)
#pragma unroll
        for (int cc = 0; cc < 8; ++cc) acc[r][cc] = 0.0f;

    const int srow = tid >> 3;            // 0..31
    const int skk  = (tid & 7) * 4;       // 0,4,..,28

    float4 pa[4], pb[4];
    GLOAD(0) SWRITE(0)
    __syncthreads();

#pragma unroll
    for (int ks = 0; ks < 4; ++ks) {
        if (ks < 3) GLOAD((ks + 1) * 32)  // prefetch next stage (in flight)

        const int buf = ks & 1;
#pragma unroll 8
        for (int kk = 0; kk < 32; ++kk) {
            const float4 a0 = *reinterpret_cast<const float4*>(&as[buf][kk][swz(ty * 8)]);
            const float4 a1 = *reinterpret_cast<const float4*>(&as[buf][kk][swz(ty * 8) + 4]);
            const float4 b0 = *reinterpret_cast<const float4*>(&bs[buf][kk][swz(tx * 8)]);
            const float4 b1 = *reinterpret_cast<const float4*>(&bs[buf][kk][swz(tx * 8) + 4]);
            const float av[8] = {a0.x, a0.y, a0.z, a0.w, a1.x, a1.y, a1.z, a1.w};
            const float bv[8] = {b0.x, b0.y, b0.z, b0.w, b1.x, b1.y, b1.z, b1.w};
#pragma unroll
            for (int r = 0; r < 8; ++r)
#pragma unroll
                for (int cc = 0; cc < 8; ++cc)
                    acc[r][cc] = fmaf(av[r], bv[cc], acc[r][cc]);
        }

        if (ks < 3) {
            SWRITE(buf ^ 1)               // prev readers of buf^1 done (bar ks-1)
            __syncthreads();              // one barrier per stage
        }
    }

#pragma unroll
    for (int r = 0; r < 8; ++r) {
        const size_t m = (size_t)(mt * 128 + ty * 8 + r);
        float4 o0 = {acc[r][0] + bia.x, acc[r][1] + bia.y,
                     acc[r][2] + bia.z, acc[r][3] + bia.w};
        float4 o1 = {acc[r][4] + bib.x, acc[r][5] + bib.y,
                     acc[r][6] + bib.z, acc[r][7] + bib.w};
        *reinterpret_cast<float4*>(&XG[m * G_SZ + n0])     = o0;
        *reinterpret_cast<float4*>(&XG[m * G_SZ + n0 + 4]) = o1;
    }
}

// ---------------------------------------------------------------------------
// Recurrence, SINGLE WAVE per batch. 64 threads; lane l owns unit l AND all
// four gate rows {l, 64+l, 128+l, 192+l}: 256 pinned weight floats (fits the
// ~450-VGPR 1-wave/SIMD budget, m08/m24). Per step: 64 readlane of h (each
// feeding 4 FMAs) + 256 FMA + in-lane activations + in-lane cell update.
// i,f,g,o never leave the lane: ZERO LDS, ZERO barriers, zero gs roundtrip
// (R11's ~950cyc step was ~650cyc barrier/LDS/redundancy overhead).
// xg: 4 coalesced global loads/step, prefetched one step (~700cyc) ahead.
// ---------------------------------------------------------------------------
__global__ __launch_bounds__(64, 1) void lstm_rec(
    const float* __restrict__ XG,     // [TC,B,256]
    const float* __restrict__ W_hh,   // [256,64]
    float* __restrict__ h_state,      // [B,64]
    float* __restrict__ c_state,      // [B,64]
    int TC, int first)
{
    const int b = blockIdx.x;
    const int l = threadIdx.x;        // lane = unit

    // 4 gate rows x 64 weights -> 32 pinned f32x8 (256 VGPRs)
    const float* ri = W_hh + (0 * H_SZ + l) * H_SZ;   // row l       (i)
    const float* rf = W_hh + (1 * H_SZ + l) * H_SZ;   // row 64+l    (f)
    const float* rg = W_hh + (2 * H_SZ + l) * H_SZ;   // row 128+l   (g)
    const float* ro = W_hh + (3 * H_SZ + l) * H_SZ;   // row 192+l   (o)
    f32x8 wi0, wi1, wi2, wi3, wi4, wi5, wi6, wi7;
    f32x8 wf0, wf1, wf2, wf3, wf4, wf5, wf6, wf7;
    f32x8 wg0, wg1, wg2, wg3, wg4, wg5, wg6, wg7;
    f32x8 wo0, wo1, wo2, wo3, wo4, wo5, wo6, wo7;
    LD8PIN(wi0, ri)      LD8PIN(wi1, ri +  8) LD8PIN(wi2, ri + 16) LD8PIN(wi3, ri + 24)
    LD8PIN(wi4, ri + 32) LD8PIN(wi5, ri + 40) LD8PIN(wi6, ri + 48) LD8PIN(wi7, ri + 56)
    LD8PIN(wf0, rf)      LD8PIN(wf1, rf +  8) LD8PIN(wf2, rf + 16) LD8PIN(wf3, rf + 24)
    LD8PIN(wf4, rf + 32) LD8PIN(wf5, rf + 40) LD8PIN(wf6, rf + 48) LD8PIN(wf7, rf + 56)
    LD8PIN(wg0, rg)      LD8PIN(wg1, rg +  8) LD8PIN(wg2, rg + 16) LD8PIN(wg3, rg + 24)
    LD8PIN(wg4, rg + 32) LD8PIN(wg5, rg + 40) LD8PIN(wg6, rg + 48) LD8PIN(wg7, rg + 56)
    LD8PIN(wo0, ro)      LD8PIN(wo1, ro +  8) LD8PIN(wo2, ro + 16) LD8PIN(wo3, ro + 24)
    LD8PIN(wo4, ro + 32) LD8PIN(wo5, ro + 40) LD8PIN(wo6, ro + 48) LD8PIN(wo7, ro + 56)

    float h = first ? 0.0f : h_state[b * H_SZ + l];
    float c = first ? 0.0f : c_state[b * H_SZ + l];

    const float* xgp = XG + (size_t)b * G_SZ;
    const size_t tstride = (size_t)B_SZ * G_SZ;

    // prologue: xg for step 0 (4 coalesced dword loads)
    float xi = xgp[l], xf = xgp[H_SZ + l], xg = xgp[2 * H_SZ + l], xo = xgp[3 * H_SZ + l];

    for (int t = 0; t < TC; ++t) {
        // prefetch next step's xg (consumed next iteration: ~700cyc of cover)
        float ni = 0.0f, nf = 0.0f, ng = 0.0f, no = 0.0f;
        if (t + 1 < TC) {
            const float* p = xgp + (size_t)(t + 1) * tstride;
            ni = p[l]; nf = p[H_SZ + l]; ng = p[2 * H_SZ + l]; no = p[3 * H_SZ + l];
        }

        // 4 gate dots: 64 readlane shared across 4 FMA streams
        const unsigned hu = __float_as_uint(h);
        float ai = xi, af = xf, ag = xg, ao = xo;
        DOT8(wi0, wf0, wg0, wo0,  0) DOT8(wi1, wf1, wg1, wo1,  8)
        DOT8(wi2, wf2, wg2, wo2, 16) DOT8(wi3, wf3, wg3, wo3, 24)
        DOT8(wi4, wf4, wg4, wo4, 32) DOT8(wi5, wf5, wg5, wo5, 40)
        DOT8(wi6, wf6, wg6, wo6, 48) DOT8(wi7, wf7, wg7, wo7, 56)

        // in-lane activations (preacts bounded |x|<~14: branchless forms safe)
        const float i_ = fast_sigmoid(ai);
        const float f_ = fast_sigmoid(af);
        const float g_ = fast_tanh_b(ag);
        const float o_ = fast_sigmoid(ao);

        // in-lane cell update (cell tanh uses the |x|-safe form)
        c = fmaf(f_, c, i_ * g_);
        h = o_ * fast_tanh(c);

        xi = ni; xf = nf; xg = ng; xo = no;
    }

    h_state[b * H_SZ + l] = h;
    c_state[b * H_SZ + l] = c;
}

// ---------------------------------------------------------------------------
// Reverse single cell (zero init state; W_hh_r drops out) + MLP head.
// ---------------------------------------------------------------------------
__global__ __launch_bounds__(256, 1) void lstm_tail(
    const float* __restrict__ x_last,  // [B,I]
    const float* __restrict__ W_ih_r,  // [256,128]
    const float* __restrict__ b_r,     // [256]
    const float* __restrict__ h_fwd,   // [B,64]
    const float* __restrict__ fc1_w,   // [64,128]
    const float* __restrict__ fc1_b,   // [64]
    const float* __restrict__ fc2_w,   // [32,64]
    const float* __restrict__ fc2_b,   // [32]
    const float* __restrict__ fc3_w,   // [10,32]
    const float* __restrict__ fc3_b,   // [10]
    float* __restrict__ out)           // [B,10]
{
    const int b = blockIdx.x;
    const int j = threadIdx.x;

    __shared__ float xs[I_SZ];
    __shared__ float gs[G_SZ];
    __shared__ float hc[2 * H_SZ];
    __shared__ float h1[64];
    __shared__ float h2[32];

    if (j < I_SZ) xs[j] = x_last[(size_t)b * I_SZ + j];
    if (j < H_SZ) hc[j] = h_fwd[b * H_SZ + j];
    __syncthreads();

    float a0 = b_r[j], a1 = 0.0f, a2 = 0.0f, a3 = 0.0f;
    const float* wrow = W_ih_r + j * I_SZ;
#pragma unroll
    for (int kk = 0; kk < I_SZ; kk += 4) {
        float4 wv = *reinterpret_cast<const float4*>(wrow + kk);
        a0 = fmaf(xs[kk + 0], wv.x, a0);
        a1 = fmaf(xs[kk + 1], wv.y, a1);
        a2 = fmaf(xs[kk + 2], wv.z, a2);
        a3 = fmaf(xs[kk + 3], wv.w, a3);
    }
    const float acc = (a0 + a1) + (a2 + a3);
    const int gate = j >> 6;
    gs[j] = (gate == 2) ? tanhf(acc) : 1.0f / (1.0f + expf(-acc));
    __syncthreads();

    if (j < H_SZ) {
        const float cc = gs[j] * gs[2 * H_SZ + j];     // i*g (c0 = 0)
        hc[H_SZ + j] = gs[3 * H_SZ + j] * tanhf(cc);
    }
    __syncthreads();

    if (j < 64) {
        float s0 = fc1_b[j], s1 = 0.0f, s2 = 0.0f, s3 = 0.0f;
        const float* w = fc1_w + j * 128;
#pragma unroll
        for (int kk = 0; kk < 128; kk += 4) {
            float4 wv = *reinterpret_cast<const float4*>(w + kk);
            s0 = fmaf(hc[kk + 0], wv.x, s0);
            s1 = fmaf(hc[kk + 1], wv.y, s1);
            s2 = fmaf(hc[kk + 2], wv.z, s2);
            s3 = fmaf(hc[kk + 3], wv.w, s3);
        }
        h1[j] = fmaxf((s0 + s1) + (s2 + s3), 0.0f);
    }
    __syncthreads();

    if (j < 32) {
        float s0 = fc2_b[j], s1 = 0.0f, s2 = 0.0f, s3 = 0.0f;
        const float* w = fc2_w + j * 64;
#pragma unroll
        for (int kk = 0; kk < 64; kk += 4) {
            float4 wv = *reinterpret_cast<const float4*>(w + kk);
            s0 = fmaf(h1[kk + 0], wv.x, s0);
            s1 = fmaf(h1[kk + 1], wv.y, s1);
            s2 = fmaf(h1[kk + 2], wv.z, s2);
            s3 = fmaf(h1[kk + 3], wv.w, s3);
        }
        h2[j] = fmaxf((s0 + s1) + (s2 + s3), 0.0f);
    }
    __syncthreads();

    if (j < 10) {
        float s = fc3_b[j];
#pragma unroll
        for (int kk = 0; kk < 32; ++kk) s = fmaf(h2[kk], fc3_w[j * 32 + kk], s);
        out[b * 10 + j] = s;
    }
}

extern "C" void kernel_launch(void* const* d_in, const int* in_sizes, int n_in,
                              void* d_out, int out_size, void* d_ws, size_t ws_size,
                              hipStream_t stream) {
    const float* x      = (const float*)d_in[0];
    const float* W_ih_f = (const float*)d_in[1];
    const float* W_hh_f = (const float*)d_in[2];
    const float* b_f    = (const float*)d_in[3];
    const float* W_ih_r = (const float*)d_in[4];
    // d_in[5] = W_hh_r : unused (zero initial state in reverse single step)
    const float* b_r    = (const float*)d_in[6];
    const float* fc1_w  = (const float*)d_in[7];
    const float* fc1_b  = (const float*)d_in[8];
    const float* fc2_w  = (const float*)d_in[9];
    const float* fc2_b  = (const float*)d_in[10];
    const float* fc3_w  = (const float*)d_in[11];
    const float* fc3_b  = (const float*)d_in[12];
    float* out = (float*)d_out;

    // time-chunk size: largest TC whose XG buffer (+state) fits in ws
    int TC = 1024;
    while (TC > 64 &&
           (size_t)TC * B_SZ * G_SZ * 4 + 2 * B_SZ * H_SZ * 4 > ws_size)
        TC >>= 1;

    float* XG      = (float*)d_ws;
    float* h_state = (float*)((char*)d_ws + (size_t)TC * B_SZ * G_SZ * 4);
    float* c_state = h_state + B_SZ * H_SZ;

    const int NCH = T_LEN / TC;
    for (int ch = 0; ch < NCH; ++ch) {
        const float* xch = x + (size_t)ch * TC * B_SZ * I_SZ;
        hipLaunchKernelGGL(xg_gemm, dim3(TC * B_SZ / 128, 2), dim3(256), 0,
                           stream, xch, W_ih_f, b_f, XG);
        hipLaunchKernelGGL(lstm_rec, dim3(B_SZ), dim3(64), 0, stream,
                           XG, W_hh_f, h_state, c_state, TC, ch == 0 ? 1 : 0);
    }

    const float* x_last = x + (size_t)(T_LEN - 1) * B_SZ * I_SZ;
    hipLaunchKernelGGL(lstm_tail, dim3(B_SZ), dim3(256), 0, stream,
                       x_last, W_ih_r, b_r, h_state,
                       fc1_w, fc1_b, fc2_w, fc2_b, fc3_w, fc3_b, out);
}

// Round 17
// 942.807 us; speedup vs baseline: 1.5923x; 1.5923x over previous
//
#include <hip/hip_runtime.h>
#include <math.h>

#define T_LEN 1024
#define B_SZ  256
#define I_SZ  128
#define H_SZ  64
#define G_SZ  256   // 4*H

typedef float f32x8 __attribute__((ext_vector_type(8)));

__device__ __forceinline__ float fast_sigmoid(float x) {  // |x|<~15 safe
    float e = __expf(-x);
    return __builtin_amdgcn_rcpf(1.0f + e);
}
__device__ __forceinline__ float fast_tanh(float x) {     // safe for any |x|
    float e = __expf(-2.0f * fabsf(x));
    float r = (1.0f - e) * __builtin_amdgcn_rcpf(1.0f + e);
    return copysignf(r, x);
}

#define LD8PIN(V, P)                                                        \
    {   float4 t0_ = *reinterpret_cast<const float4*>(P);                   \
        float4 t1_ = *reinterpret_cast<const float4*>((P) + 4);             \
        V = (f32x8){t0_.x, t0_.y, t0_.z, t0_.w, t1_.x, t1_.y, t1_.z, t1_.w};\
        asm volatile("" : "+v"(V)); }

// One readlane of h[k] feeds TWO gate-row FMAs (rows A and B). K literal:
// readlane lane-index must be wave-uniform (R12 lesson).
#define DOT8_2(VA, VB, K)                                                   \
    { _Pragma("unroll") for (int q_ = 0; q_ < 8; ++q_) {                    \
        unsigned s_ = __builtin_amdgcn_readlane(hu, (K) + q_);              \
        const float hv_ = __uint_as_float(s_);                              \
        if ((q_ & 3) == 0) { aA0 = fmaf(hv_, VA[q_], aA0);                  \
                             aB0 = fmaf(hv_, VB[q_], aB0); }                \
        else if ((q_ & 3) == 1) { aA1 = fmaf(hv_, VA[q_], aA1);             \
                                  aB1 = fmaf(hv_, VB[q_], aB1); }           \
        else if ((q_ & 3) == 2) { aA2 = fmaf(hv_, VA[q_], aA2);             \
                                  aB2 = fmaf(hv_, VB[q_], aB2); }           \
        else { aA3 = fmaf(hv_, VA[q_], aA3);                                \
               aB3 = fmaf(hv_, VB[q_], aB3); } } }

// LDS column swizzle for the GEMM tiles
__device__ __forceinline__ int swz(int c) { return c + 4 * (c >> 5); }

// GEMM staging: global -> regs (issued early, latency hidden under compute)
#define GLOAD(K0)                                                           \
    { _Pragma("unroll") for (int i_ = 0; i_ < 4; ++i_) {                    \
        const int mr_ = srow + 32 * i_;                                     \
        pa[i_] = *reinterpret_cast<const float4*>(                          \
            &xch[(size_t)(mt * 128 + mr_) * I_SZ + (K0) + skk]);            \
        pb[i_] = *reinterpret_cast<const float4*>(                          \
            &W_ih[(size_t)(nt * 128 + mr_) * I_SZ + (K0) + skk]); } }

// GEMM staging: regs -> LDS (after compute; one barrier per stage)
#define SWRITE(BUF)                                                         \
    { _Pragma("unroll") for (int i_ = 0; i_ < 4; ++i_) {                    \
        const int mr_ = srow + 32 * i_; const int sm_ = swz(mr_);           \
        as[BUF][skk + 0][sm_] = pa[i_].x; as[BUF][skk + 1][sm_] = pa[i_].y; \
        as[BUF][skk + 2][sm_] = pa[i_].z; as[BUF][skk + 3][sm_] = pa[i_].w; \
        bs[BUF][skk + 0][sm_] = pb[i_].x; bs[BUF][skk + 1][sm_] = pb[i_].y; \
        bs[BUF][skk + 2][sm_] = pb[i_].z; bs[BUF][skk + 3][sm_] = pb[i_].w; } }

// ---------------------------------------------------------------------------
// XG GEMM, double-buffered (unchanged, R13: ~190us)
// ---------------------------------------------------------------------------
__global__ __launch_bounds__(256, 2) void xg_gemm(
    const float* __restrict__ xch,    // [Mc,128] chunk of x
    const float* __restrict__ W_ih,   // [256,128]
    const float* __restrict__ bias,   // [256]
    float* __restrict__ XG)           // [Mc,256]
{
    const int tid = threadIdx.x;
    const int tx  = tid & 15;
    const int ty  = tid >> 4;
    const int mt  = blockIdx.x;
    const int nt  = blockIdx.y;

    __shared__ __align__(16) float as[2][32][140];   // 35.8 KB
    __shared__ __align__(16) float bs[2][32][140];   // 35.8 KB

    const int n0 = nt * 128 + tx * 8;
    float4 bia = *reinterpret_cast<const float4*>(&bias[n0]);
    float4 bib = *reinterpret_cast<const float4*>(&bias[n0 + 4]);

    float acc[8][8];
#pragma unroll
    for (int r = 0; r < 8; ++r)
#pragma unroll
        for (int cc = 0; cc < 8; ++cc) acc[r][cc] = 0.0f;

    const int srow = tid >> 3;            // 0..31
    const int skk  = (tid & 7) * 4;       // 0,4,..,28

    float4 pa[4], pb[4];
    GLOAD(0) SWRITE(0)
    __syncthreads();

#pragma unroll
    for (int ks = 0; ks < 4; ++ks) {
        if (ks < 3) GLOAD((ks + 1) * 32)  // prefetch next stage (in flight)

        const int buf = ks & 1;
#pragma unroll 8
        for (int kk = 0; kk < 32; ++kk) {
            const float4 a0 = *reinterpret_cast<const float4*>(&as[buf][kk][swz(ty * 8)]);
            const float4 a1 = *reinterpret_cast<const float4*>(&as[buf][kk][swz(ty * 8) + 4]);
            const float4 b0 = *reinterpret_cast<const float4*>(&bs[buf][kk][swz(tx * 8)]);
            const float4 b1 = *reinterpret_cast<const float4*>(&bs[buf][kk][swz(tx * 8) + 4]);
            const float av[8] = {a0.x, a0.y, a0.z, a0.w, a1.x, a1.y, a1.z, a1.w};
            const float bv[8] = {b0.x, b0.y, b0.z, b0.w, b1.x, b1.y, b1.z, b1.w};
#pragma unroll
            for (int r = 0; r < 8; ++r)
#pragma unroll
                for (int cc = 0; cc < 8; ++cc)
                    acc[r][cc] = fmaf(av[r], bv[cc], acc[r][cc]);
        }

        if (ks < 3) {
            SWRITE(buf ^ 1)               // prev readers of buf^1 done (bar ks-1)
            __syncthreads();              // one barrier per stage
        }
    }

#pragma unroll
    for (int r = 0; r < 8; ++r) {
        const size_t m = (size_t)(mt * 128 + ty * 8 + r);
        float4 o0 = {acc[r][0] + bia.x, acc[r][1] + bia.y,
                     acc[r][2] + bia.z, acc[r][3] + bia.w};
        float4 o1 = {acc[r][4] + bib.x, acc[r][5] + bib.y,
                     acc[r][6] + bib.z, acc[r][7] + bib.w};
        *reinterpret_cast<float4*>(&XG[m * G_SZ + n0])     = o0;
        *reinterpret_cast<float4*>(&XG[m * G_SZ + n0 + 4]) = o1;
    }
}

// ---------------------------------------------------------------------------
// Recurrence: 2 waves per batch, 2 gates per lane (128 pinned weights/lane —
// UNDER the 256 v-reg architectural cap that sank R16's 256-float version).
// Wave 0 lane l owns rows {l (i), 128+l (g)}; wave 1 owns {64+l (f), 192+l
// (o)}. Per step: 64 readlane (each feeding 2 FMAs) + 128 FMA + 2 in-lane
// activations + 4x64 LDS gate exchange (double-buffered, ONE 2-wave barrier)
// + replicated in-lane cell update. xg direct from global w/ 1-step prefetch
// (R16-proven path). No xgl staging, no gs round-trip.
// ---------------------------------------------------------------------------
__global__ __launch_bounds__(128, 1) void lstm_rec(
    const float* __restrict__ XG,     // [TC,B,256]
    const float* __restrict__ W_hh,   // [256,64]
    float* __restrict__ h_state,      // [B,64]
    float* __restrict__ c_state,      // [B,64]
    int TC, int first)
{
    const int b   = blockIdx.x;
    const int tid = threadIdx.x;
    const int l   = tid & 63;         // lane = unit
    const int w   = tid >> 6;         // 0: {i,g}, 1: {f,o}  (wave-uniform)

    __shared__ float ex[2][4][H_SZ];  // [db][gate i,f,g,o][unit] — 2 KB

    // two full W_hh rows -> 128 pinned register floats
    const int rowA = w * 64 + l;          // i (w0) / f (w1)
    const int rowB = 128 + w * 64 + l;    // g (w0) / o (w1)
    const float* ra = W_hh + rowA * H_SZ;
    const float* rb = W_hh + rowB * H_SZ;
    f32x8 wa0, wa1, wa2, wa3, wa4, wa5, wa6, wa7;
    f32x8 wb0, wb1, wb2, wb3, wb4, wb5, wb6, wb7;
    LD8PIN(wa0, ra)      LD8PIN(wa1, ra +  8) LD8PIN(wa2, ra + 16) LD8PIN(wa3, ra + 24)
    LD8PIN(wa4, ra + 32) LD8PIN(wa5, ra + 40) LD8PIN(wa6, ra + 48) LD8PIN(wa7, ra + 56)
    LD8PIN(wb0, rb)      LD8PIN(wb1, rb +  8) LD8PIN(wb2, rb + 16) LD8PIN(wb3, rb + 24)
    LD8PIN(wb4, rb + 32) LD8PIN(wb5, rb + 40) LD8PIN(wb6, rb + 48) LD8PIN(wb7, rb + 56)

    // replicated state (both waves: lane l = unit l)
    float h = first ? 0.0f : h_state[b * H_SZ + l];
    float c = first ? 0.0f : c_state[b * H_SZ + l];

    const float* xgp = XG + (size_t)b * G_SZ;
    const size_t tstride = (size_t)B_SZ * G_SZ;

    // prologue: xg for step 0 (2 coalesced dword loads per wave)
    float xgA = xgp[rowA], xgB = xgp[rowB];

    const bool Btanh = (w == 0);      // wave-uniform: row B is g-gate on w0
    int db = 0;

    for (int ts = 0; ts < TC; ++ts) {
        // prefetch next step's xg (consumed next iteration)
        float nA = 0.0f, nB = 0.0f;
        if (ts + 1 < TC) {
            const float* p = xgp + (size_t)(ts + 1) * tstride;
            nA = p[rowA]; nB = p[rowB];
        }

        // two gate dots: 64 readlane shared across 2 FMA streams, 4 chains ea
        const unsigned hu = __float_as_uint(h);
        float aA0 = xgA, aA1 = 0.0f, aA2 = 0.0f, aA3 = 0.0f;
        float aB0 = xgB, aB1 = 0.0f, aB2 = 0.0f, aB3 = 0.0f;
        DOT8_2(wa0, wb0,  0) DOT8_2(wa1, wb1,  8)
        DOT8_2(wa2, wb2, 16) DOT8_2(wa3, wb3, 24)
        DOT8_2(wa4, wb4, 32) DOT8_2(wa5, wb5, 40)
        DOT8_2(wa6, wb6, 48) DOT8_2(wa7, wb7, 56)
        const float accA = (aA0 + aA1) + (aA2 + aA3);
        const float accB = (aB0 + aB1) + (aB2 + aB3);

        // in-lane activations (preacts bounded; branchless select on B)
        const float actA = fast_sigmoid(accA);            // i (w0) / f (w1)
        const float argB = Btanh ? (-2.0f * accB) : (-accB);
        const float eB = __expf(argB);
        const float rB = __builtin_amdgcn_rcpf(1.0f + eB);
        const float actB = Btanh ? (1.0f - eB) * rB : rB; // g (w0) / o (w1)

        // exchange: w0 publishes {i,g}, w1 publishes {f,o}
        ex[db][w][l]     = actA;      // gate index: 0=i, 1=f
        ex[db][2 + w][l] = actB;      // gate index: 2=g, 3=o
        __syncthreads();              // 2-wave barrier

        const float oa = ex[db][1 - w][l];      // w0: f | w1: i
        const float ob = ex[db][3 - w][l];      // w0: o | w1: g
        float i_, f_, g_, o_;
        if (w == 0) { i_ = actA; g_ = actB; f_ = oa; o_ = ob; }
        else        { f_ = actA; o_ = actB; i_ = oa; g_ = ob; }

        // replicated cell update (identical bits on both waves)
        c = fmaf(f_, c, i_ * g_);
        h = o_ * fast_tanh(c);

        db ^= 1;
        xgA = nA; xgB = nB;
    }

    if (w == 0) {
        h_state[b * H_SZ + l] = h;
        c_state[b * H_SZ + l] = c;
    }
}

// ---------------------------------------------------------------------------
// Reverse single cell (zero init state; W_hh_r drops out) + MLP head.
// ---------------------------------------------------------------------------
__global__ __launch_bounds__(256, 1) void lstm_tail(
    const float* __restrict__ x_last,  // [B,I]
    const float* __restrict__ W_ih_r,  // [256,128]
    const float* __restrict__ b_r,     // [256]
    const float* __restrict__ h_fwd,   // [B,64]
    const float* __restrict__ fc1_w,   // [64,128]
    const float* __restrict__ fc1_b,   // [64]
    const float* __restrict__ fc2_w,   // [32,64]
    const float* __restrict__ fc2_b,   // [32]
    const float* __restrict__ fc3_w,   // [10,32]
    const float* __restrict__ fc3_b,   // [10]
    float* __restrict__ out)           // [B,10]
{
    const int b = blockIdx.x;
    const int j = threadIdx.x;

    __shared__ float xs[I_SZ];
    __shared__ float gs[G_SZ];
    __shared__ float hc[2 * H_SZ];
    __shared__ float h1[64];
    __shared__ float h2[32];

    if (j < I_SZ) xs[j] = x_last[(size_t)b * I_SZ + j];
    if (j < H_SZ) hc[j] = h_fwd[b * H_SZ + j];
    __syncthreads();

    float a0 = b_r[j], a1 = 0.0f, a2 = 0.0f, a3 = 0.0f;
    const float* wrow = W_ih_r + j * I_SZ;
#pragma unroll
    for (int kk = 0; kk < I_SZ; kk += 4) {
        float4 wv = *reinterpret_cast<const float4*>(wrow + kk);
        a0 = fmaf(xs[kk + 0], wv.x, a0);
        a1 = fmaf(xs[kk + 1], wv.y, a1);
        a2 = fmaf(xs[kk + 2], wv.z, a2);
        a3 = fmaf(xs[kk + 3], wv.w, a3);
    }
    const float acc = (a0 + a1) + (a2 + a3);
    const int gate = j >> 6;
    gs[j] = (gate == 2) ? tanhf(acc) : 1.0f / (1.0f + expf(-acc));
    __syncthreads();

    if (j < H_SZ) {
        const float cc = gs[j] * gs[2 * H_SZ + j];     // i*g (c0 = 0)
        hc[H_SZ + j] = gs[3 * H_SZ + j] * tanhf(cc);
    }
    __syncthreads();

    if (j < 64) {
        float s0 = fc1_b[j], s1 = 0.0f, s2 = 0.0f, s3 = 0.0f;
        const float* w = fc1_w + j * 128;
#pragma unroll
        for (int kk = 0; kk < 128; kk += 4) {
            float4 wv = *reinterpret_cast<const float4*>(w + kk);
            s0 = fmaf(hc[kk + 0], wv.x, s0);
            s1 = fmaf(hc[kk + 1], wv.y, s1);
            s2 = fmaf(hc[kk + 2], wv.z, s2);
            s3 = fmaf(hc[kk + 3], wv.w, s3);
        }
        h1[j] = fmaxf((s0 + s1) + (s2 + s3), 0.0f);
    }
    __syncthreads();

    if (j < 32) {
        float s0 = fc2_b[j], s1 = 0.0f, s2 = 0.0f, s3 = 0.0f;
        const float* w = fc2_w + j * 64;
#pragma unroll
        for (int kk = 0; kk < 64; kk += 4) {
            float4 wv = *reinterpret_cast<const float4*>(w + kk);
            s0 = fmaf(h1[kk + 0], wv.x, s0);
            s1 = fmaf(h1[kk + 1], wv.y, s1);
            s2 = fmaf(h1[kk + 2], wv.z, s2);
            s3 = fmaf(h1[kk + 3], wv.w, s3);
        }
        h2[j] = fmaxf((s0 + s1) + (s2 + s3), 0.0f);
    }
    __syncthreads();

    if (j < 10) {
        float s = fc3_b[j];
#pragma unroll
        for (int kk = 0; kk < 32; ++kk) s = fmaf(h2[kk], fc3_w[j * 32 + kk], s);
        out[b * 10 + j] = s;
    }
}

extern "C" void kernel_launch(void* const* d_in, const int* in_sizes, int n_in,
                              void* d_out, int out_size, void* d_ws, size_t ws_size,
                              hipStream_t stream) {
    const float* x      = (const float*)d_in[0];
    const float* W_ih_f = (const float*)d_in[1];
    const float* W_hh_f = (const float*)d_in[2];
    const float* b_f    = (const float*)d_in[3];
    const float* W_ih_r = (const float*)d_in[4];
    // d_in[5] = W_hh_r : unused (zero initial state in reverse single step)
    const float* b_r    = (const float*)d_in[6];
    const float* fc1_w  = (const float*)d_in[7];
    const float* fc1_b  = (const float*)d_in[8];
    const float* fc2_w  = (const float*)d_in[9];
    const float* fc2_b  = (const float*)d_in[10];
    const float* fc3_w  = (const float*)d_in[11];
    const float* fc3_b  = (const float*)d_in[12];
    float* out = (float*)d_out;

    // time-chunk size: largest TC whose XG buffer (+state) fits in ws
    int TC = 1024;
    while (TC > 64 &&
           (size_t)TC * B_SZ * G_SZ * 4 + 2 * B_SZ * H_SZ * 4 > ws_size)
        TC >>= 1;

    float* XG      = (float*)d_ws;
    float* h_state = (float*)((char*)d_ws + (size_t)TC * B_SZ * G_SZ * 4);
    float* c_state = h_state + B_SZ * H_SZ;

    const int NCH = T_LEN / TC;
    for (int ch = 0; ch < NCH; ++ch) {
        const float* xch = x + (size_t)ch * TC * B_SZ * I_SZ;
        hipLaunchKernelGGL(xg_gemm, dim3(TC * B_SZ / 128, 2), dim3(256), 0,
                           stream, xch, W_ih_f, b_f, XG);
        hipLaunchKernelGGL(lstm_rec, dim3(B_SZ), dim3(128), 0, stream,
                           XG, W_hh_f, h_state, c_state, TC, ch == 0 ? 1 : 0);
    }

    const float* x_last = x + (size_t)(T_LEN - 1) * B_SZ * I_SZ;
    hipLaunchKernelGGL(lstm_tail, dim3(B_SZ), dim3(256), 0, stream,
                       x_last, W_ih_r, b_r, h_state,
                       fc1_w, fc1_b, fc2_w, fc2_b, fc3_w, fc3_b, out);
}

// Round 18
// 607.069 us; speedup vs baseline: 2.4729x; 1.5530x over previous
//
#include <hip/hip_runtime.h>
#include <math.h>

#define T_LEN 1024
#define B_SZ  256
#define I_SZ  128
#define H_SZ  64
#define G_SZ  256   // 4*H
#define SUB   32    // recurrence steps per LDS-staged XG sub-chunk

typedef float f32x8 __attribute__((ext_vector_type(8)));
typedef float f32x2 __attribute__((ext_vector_type(2)));

__device__ __forceinline__ float fast_tanh(float x) {   // safe for any |x|
    float e = __expf(-2.0f * fabsf(x));
    float r = (1.0f - e) * __builtin_amdgcn_rcpf(1.0f + e);
    return copysignf(r, x);
}

#define LD8PIN(V, P)                                                        \
    {   float4 t0_ = *reinterpret_cast<const float4*>(P);                   \
        float4 t1_ = *reinterpret_cast<const float4*>((P) + 4);             \
        V = (f32x8){t0_.x, t0_.y, t0_.z, t0_.w, t1_.x, t1_.y, t1_.z, t1_.w};\
        asm volatile("" : "+v"(V)); }

// acc(4 chains) += h[K..K+15]*{VA,VB}; h via v_readlane with LITERAL indices
// (R12 lesson: divergent lane index = UB). 16 readlanes hoisted before FMAs.
#define RL16(VA, VB, K)                                                     \
    {   unsigned s0_  = __builtin_amdgcn_readlane(hu, (K) + 0);             \
        unsigned s1_  = __builtin_amdgcn_readlane(hu, (K) + 1);             \
        unsigned s2_  = __builtin_amdgcn_readlane(hu, (K) + 2);             \
        unsigned s3_  = __builtin_amdgcn_readlane(hu, (K) + 3);             \
        unsigned s4_  = __builtin_amdgcn_readlane(hu, (K) + 4);             \
        unsigned s5_  = __builtin_amdgcn_readlane(hu, (K) + 5);             \
        unsigned s6_  = __builtin_amdgcn_readlane(hu, (K) + 6);             \
        unsigned s7_  = __builtin_amdgcn_readlane(hu, (K) + 7);             \
        unsigned s8_  = __builtin_amdgcn_readlane(hu, (K) + 8);             \
        unsigned s9_  = __builtin_amdgcn_readlane(hu, (K) + 9);             \
        unsigned s10_ = __builtin_amdgcn_readlane(hu, (K) + 10);            \
        unsigned s11_ = __builtin_amdgcn_readlane(hu, (K) + 11);            \
        unsigned s12_ = __builtin_amdgcn_readlane(hu, (K) + 12);            \
        unsigned s13_ = __builtin_amdgcn_readlane(hu, (K) + 13);            \
        unsigned s14_ = __builtin_amdgcn_readlane(hu, (K) + 14);            \
        unsigned s15_ = __builtin_amdgcn_readlane(hu, (K) + 15);            \
        a0 = fmaf(__uint_as_float(s0_),  VA[0], a0);                        \
        a1 = fmaf(__uint_as_float(s1_),  VA[1], a1);                        \
        a2 = fmaf(__uint_as_float(s2_),  VA[2], a2);                        \
        a3 = fmaf(__uint_as_float(s3_),  VA[3], a3);                        \
        a0 = fmaf(__uint_as_float(s4_),  VA[4], a0);                        \
        a1 = fmaf(__uint_as_float(s5_),  VA[5], a1);                        \
        a2 = fmaf(__uint_as_float(s6_),  VA[6], a2);                        \
        a3 = fmaf(__uint_as_float(s7_),  VA[7], a3);                        \
        a0 = fmaf(__uint_as_float(s8_),  VB[0], a0);                        \
        a1 = fmaf(__uint_as_float(s9_),  VB[1], a1);                        \
        a2 = fmaf(__uint_as_float(s10_), VB[2], a2);                        \
        a3 = fmaf(__uint_as_float(s11_), VB[3], a3);                        \
        a0 = fmaf(__uint_as_float(s12_), VB[4], a0);                        \
        a1 = fmaf(__uint_as_float(s13_), VB[5], a1);                        \
        a2 = fmaf(__uint_as_float(s14_), VB[6], a2);                        \
        a3 = fmaf(__uint_as_float(s15_), VB[7], a3); }

// LDS column swizzle for the GEMM tiles
__device__ __forceinline__ int swz(int c) { return c + 4 * (c >> 5); }

// GEMM staging: global -> regs (issued early, latency hidden under compute)
#define GLOAD(K0)                                                           \
    { _Pragma("unroll") for (int i_ = 0; i_ < 4; ++i_) {                    \
        const int mr_ = srow + 32 * i_;                                     \
        pa[i_] = *reinterpret_cast<const float4*>(                          \
            &xch[(size_t)(mt * 128 + mr_) * I_SZ + (K0) + skk]);            \
        pb[i_] = *reinterpret_cast<const float4*>(                          \
            &W_ih[(size_t)(nt * 128 + mr_) * I_SZ + (K0) + skk]); } }

// GEMM staging: regs -> LDS (after compute; one barrier per stage)
#define SWRITE(BUF)                                                         \
    { _Pragma("unroll") for (int i_ = 0; i_ < 4; ++i_) {                    \
        const int mr_ = srow + 32 * i_; const int sm_ = swz(mr_);           \
        as[BUF][skk + 0][sm_] = pa[i_].x; as[BUF][skk + 1][sm_] = pa[i_].y; \
        as[BUF][skk + 2][sm_] = pa[i_].z; as[BUF][skk + 3][sm_] = pa[i_].w; \
        bs[BUF][skk + 0][sm_] = pb[i_].x; bs[BUF][skk + 1][sm_] = pb[i_].y; \
        bs[BUF][skk + 2][sm_] = pb[i_].z; bs[BUF][skk + 3][sm_] = pb[i_].w; } }

// ---------------------------------------------------------------------------
// XG GEMM, double-buffered + f32x2 packed accumulate (v_pk_fma_f32: 2 FMA /
// instr, ~40% less VALU issue in the inner loop). Per-output summation order
// unchanged vs scalar version -> identical absmax.
// ---------------------------------------------------------------------------
__global__ __launch_bounds__(256, 2) void xg_gemm(
    const float* __restrict__ xch,    // [Mc,128] chunk of x
    const float* __restrict__ W_ih,   // [256,128]
    const float* __restrict__ bias,   // [256]
    float* __restrict__ XG)           // [Mc,256]
{
    const int tid = threadIdx.x;
    const int tx  = tid & 15;
    const int ty  = tid >> 4;
    const int mt  = blockIdx.x;
    const int nt  = blockIdx.y;

    __shared__ __align__(16) float as[2][32][140];   // 35.8 KB
    __shared__ __align__(16) float bs[2][32][140];   // 35.8 KB

    const int n0 = nt * 128 + tx * 8;
    float4 bia = *reinterpret_cast<const float4*>(&bias[n0]);
    float4 bib = *reinterpret_cast<const float4*>(&bias[n0 + 4]);

    f32x2 acc2[8][4];
#pragma unroll
    for (int r = 0; r < 8; ++r)
#pragma unroll
        for (int cc = 0; cc < 4; ++cc) acc2[r][cc] = (f32x2){0.0f, 0.0f};

    const int srow = tid >> 3;            // 0..31
    const int skk  = (tid & 7) * 4;       // 0,4,..,28

    float4 pa[4], pb[4];
    GLOAD(0) SWRITE(0)
    __syncthreads();

#pragma unroll
    for (int ks = 0; ks < 4; ++ks) {
        if (ks < 3) GLOAD((ks + 1) * 32)  // prefetch next stage (in flight)

        const int buf = ks & 1;
#pragma unroll 8
        for (int kk = 0; kk < 32; ++kk) {
            const float4 a0 = *reinterpret_cast<const float4*>(&as[buf][kk][swz(ty * 8)]);
            const float4 a1 = *reinterpret_cast<const float4*>(&as[buf][kk][swz(ty * 8) + 4]);
            const float4 b0 = *reinterpret_cast<const float4*>(&bs[buf][kk][swz(tx * 8)]);
            const float4 b1 = *reinterpret_cast<const float4*>(&bs[buf][kk][swz(tx * 8) + 4]);
            const float av[8] = {a0.x, a0.y, a0.z, a0.w, a1.x, a1.y, a1.z, a1.w};
            const f32x2 bv2[4] = {{b0.x, b0.y}, {b0.z, b0.w},
                                  {b1.x, b1.y}, {b1.z, b1.w}};
#pragma unroll
            for (int r = 0; r < 8; ++r) {
                const f32x2 a2 = {av[r], av[r]};
#pragma unroll
                for (int cc = 0; cc < 4; ++cc)
                    acc2[r][cc] = a2 * bv2[cc] + acc2[r][cc];  // v_pk_fma_f32
            }
        }

        if (ks < 3) {
            SWRITE(buf ^ 1)               // prev readers of buf^1 done (bar ks-1)
            __syncthreads();              // one barrier per stage
        }
    }

#pragma unroll
    for (int r = 0; r < 8; ++r) {
        const size_t m = (size_t)(mt * 128 + ty * 8 + r);
        float4 o0 = {acc2[r][0].x + bia.x, acc2[r][0].y + bia.y,
                     acc2[r][1].x + bia.z, acc2[r][1].y + bia.w};
        float4 o1 = {acc2[r][2].x + bib.x, acc2[r][2].y + bib.y,
                     acc2[r][3].x + bib.z, acc2[r][3].y + bib.w};
        *reinterpret_cast<float4*>(&XG[m * G_SZ + n0])     = o0;
        *reinterpret_cast<float4*>(&XG[m * G_SZ + n0 + 4]) = o1;
    }
}

// ---------------------------------------------------------------------------
// Recurrence (R15 verbatim — proven 404us, absmax 1.9e-6, VGPR 88).
// 256 threads (4 waves, wave = gate). Lane l of wave g owns full gate row
// g*64+l: 64 W_hh floats pinned (the empirically-proven RA residency limit).
// h/c REPLICATED per wave in lane registers (lane l = unit l). h-dot via
// v_readlane (literal indices) -> SGPR folds into v_fma: zero LDS for h.
// ---------------------------------------------------------------------------
__global__ __launch_bounds__(256, 1) void lstm_rec(
    const float* __restrict__ XG,     // [TC,B,256]
    const float* __restrict__ W_hh,   // [256,64]
    float* __restrict__ h_state,      // [B,64]
    float* __restrict__ c_state,      // [B,64]
    int TC, int first)
{
    const int b = blockIdx.x;
    const int t = threadIdx.x;
    const int l = t & 63;             // lane = unit (cell phase)
    const int g = t >> 6;             // wave = gate: 0=i 1=f 2=g 3=o
    const int row = t;                // gate row g*64+l

    __shared__ __align__(16) float xgl[2][SUB][G_SZ];   // 64 KB
    __shared__ float gs[2][G_SZ];                       // double-buffered gates

    // full W_hh row -> 64 pinned register floats (R8-proven resident)
    const float* ur = W_hh + row * H_SZ;
    f32x8 w0, w1, w2, w3, w4, w5, w6, w7;
    LD8PIN(w0, ur)      LD8PIN(w1, ur +  8) LD8PIN(w2, ur + 16) LD8PIN(w3, ur + 24)
    LD8PIN(w4, ur + 32) LD8PIN(w5, ur + 40) LD8PIN(w6, ur + 48) LD8PIN(w7, ur + 56)

    // replicated state in lane registers (every wave: lane l = unit l)
    float h = first ? 0.0f : h_state[b * H_SZ + l];
    float c = first ? 0.0f : c_state[b * H_SZ + l];

    // stage sub-chunk 0: flat coalesced copy (thread t copies f4 #t+256i)
    {
        float* xf = &xgl[0][0][0];
#pragma unroll
        for (int i = 0; i < 8; ++i) {
            const int F = t + 256 * i;            // float4 index 0..2047
            const int r = F >> 6, cw = F & 63;    // step row, float4 col
            *reinterpret_cast<float4*>(xf + 4 * F) =
                *reinterpret_cast<const float4*>(
                    XG + ((size_t)r * B_SZ + b) * G_SZ + 4 * cw);
        }
    }
    __syncthreads();

    const bool isg = (g == 2);        // wave-uniform
    const int nsub = TC / SUB;
    int db = 0;

    for (int sub = 0; sub < nsub; ++sub) {
        const int cur = sub & 1;
        if (sub + 1 < nsub) {         // stage next sub-chunk (flat copy)
            float* xf = &xgl[cur ^ 1][0][0];
#pragma unroll
            for (int i = 0; i < 8; ++i) {
                const int F = t + 256 * i;
                const int r = (F >> 6) + (sub + 1) * SUB, cw = F & 63;
                *reinterpret_cast<float4*>(xf + 4 * F) =
                    *reinterpret_cast<const float4*>(
                        XG + ((size_t)r * B_SZ + b) * G_SZ + 4 * cw);
            }
        }

#pragma unroll 4
        for (int ts = 0; ts < SUB; ++ts) {
            // h-dot: 64 readlane + 64 FMA (VALU only), hoisted by 16s
            const unsigned hu = __float_as_uint(h);
            float a0 = xgl[cur][ts][row];         // xg seed (banks 0..31, free)
            float a1 = 0.0f, a2 = 0.0f, a3 = 0.0f;
            RL16(w0, w1,  0) RL16(w2, w3, 16)
            RL16(w4, w5, 32) RL16(w6, w7, 48)
            const float acc = (a0 + a1) + (a2 + a3);

            // activation (wave-uniform gate; branchless select)
            const float arg = isg ? (-2.0f * acc) : (-acc);
            const float e = __expf(arg);
            const float r = __builtin_amdgcn_rcpf(1.0f + e);
            const float a = isg ? (1.0f - e) * r : r;

            gs[db][row] = a;                      // banks 0..31, conflict-free
            __syncthreads();                      // gates visible

            // replicated cell update: lane l handles unit l (4 free b32 reads)
            const float ig = gs[db][l];
            const float fg = gs[db][H_SZ + l];
            const float gg = gs[db][2 * H_SZ + l];
            const float og = gs[db][3 * H_SZ + l];
            c = fmaf(fg, c, ig * gg);
            h = og * fast_tanh(c);                // stays in registers
            db ^= 1;
        }
    }

    if (t < H_SZ) {                               // wave 0 writes final state
        h_state[b * H_SZ + t] = h;
        c_state[b * H_SZ + t] = c;
    }
}

// ---------------------------------------------------------------------------
// Reverse single cell (zero init state; W_hh_r drops out) + MLP head.
// ---------------------------------------------------------------------------
__global__ __launch_bounds__(256, 1) void lstm_tail(
    const float* __restrict__ x_last,  // [B,I]
    const float* __restrict__ W_ih_r,  // [256,128]
    const float* __restrict__ b_r,     // [256]
    const float* __restrict__ h_fwd,   // [B,64]
    const float* __restrict__ fc1_w,   // [64,128]
    const float* __restrict__ fc1_b,   // [64]
    const float* __restrict__ fc2_w,   // [32,64]
    const float* __restrict__ fc2_b,   // [32]
    const float* __restrict__ fc3_w,   // [10,32]
    const float* __restrict__ fc3_b,   // [10]
    float* __restrict__ out)           // [B,10]
{
    const int b = blockIdx.x;
    const int j = threadIdx.x;

    __shared__ float xs[I_SZ];
    __shared__ float gs[G_SZ];
    __shared__ float hc[2 * H_SZ];
    __shared__ float h1[64];
    __shared__ float h2[32];

    if (j < I_SZ) xs[j] = x_last[(size_t)b * I_SZ + j];
    if (j < H_SZ) hc[j] = h_fwd[b * H_SZ + j];
    __syncthreads();

    float a0 = b_r[j], a1 = 0.0f, a2 = 0.0f, a3 = 0.0f;
    const float* wrow = W_ih_r + j * I_SZ;
#pragma unroll
    for (int kk = 0; kk < I_SZ; kk += 4) {
        float4 wv = *reinterpret_cast<const float4*>(wrow + kk);
        a0 = fmaf(xs[kk + 0], wv.x, a0);
        a1 = fmaf(xs[kk + 1], wv.y, a1);
        a2 = fmaf(xs[kk + 2], wv.z, a2);
        a3 = fmaf(xs[kk + 3], wv.w, a3);
    }
    const float acc = (a0 + a1) + (a2 + a3);
    const int gate = j >> 6;
    gs[j] = (gate == 2) ? tanhf(acc) : 1.0f / (1.0f + expf(-acc));
    __syncthreads();

    if (j < H_SZ) {
        const float cc = gs[j] * gs[2 * H_SZ + j];     // i*g (c0 = 0)
        hc[H_SZ + j] = gs[3 * H_SZ + j] * tanhf(cc);
    }
    __syncthreads();

    if (j < 64) {
        float s0 = fc1_b[j], s1 = 0.0f, s2 = 0.0f, s3 = 0.0f;
        const float* w = fc1_w + j * 128;
#pragma unroll
        for (int kk = 0; kk < 128; kk += 4) {
            float4 wv = *reinterpret_cast<const float4*>(w + kk);
            s0 = fmaf(hc[kk + 0], wv.x, s0);
            s1 = fmaf(hc[kk + 1], wv.y, s1);
            s2 = fmaf(hc[kk + 2], wv.z, s2);
            s3 = fmaf(hc[kk + 3], wv.w, s3);
        }
        h1[j] = fmaxf((s0 + s1) + (s2 + s3), 0.0f);
    }
    __syncthreads();

    if (j < 32) {
        float s0 = fc2_b[j], s1 = 0.0f, s2 = 0.0f, s3 = 0.0f;
        const float* w = fc2_w + j * 64;
#pragma unroll
        for (int kk = 0; kk < 64; kk += 4) {
            float4 wv = *reinterpret_cast<const float4*>(w + kk);
            s0 = fmaf(h1[kk + 0], wv.x, s0);
            s1 = fmaf(h1[kk + 1], wv.y, s1);
            s2 = fmaf(h1[kk + 2], wv.z, s2);
            s3 = fmaf(h1[kk + 3], wv.w, s3);
        }
        h2[j] = fmaxf((s0 + s1) + (s2 + s3), 0.0f);
    }
    __syncthreads();

    if (j < 10) {
        float s = fc3_b[j];
#pragma unroll
        for (int kk = 0; kk < 32; ++kk) s = fmaf(h2[kk], fc3_w[j * 32 + kk], s);
        out[b * 10 + j] = s;
    }
}

extern "C" void kernel_launch(void* const* d_in, const int* in_sizes, int n_in,
                              void* d_out, int out_size, void* d_ws, size_t ws_size,
                              hipStream_t stream) {
    const float* x      = (const float*)d_in[0];
    const float* W_ih_f = (const float*)d_in[1];
    const float* W_hh_f = (const float*)d_in[2];
    const float* b_f    = (const float*)d_in[3];
    const float* W_ih_r = (const float*)d_in[4];
    // d_in[5] = W_hh_r : unused (zero initial state in reverse single step)
    const float* b_r    = (const float*)d_in[6];
    const float* fc1_w  = (const float*)d_in[7];
    const float* fc1_b  = (const float*)d_in[8];
    const float* fc2_w  = (const float*)d_in[9];
    const float* fc2_b  = (const float*)d_in[10];
    const float* fc3_w  = (const float*)d_in[11];
    const float* fc3_b  = (const float*)d_in[12];
    float* out = (float*)d_out;

    // time-chunk size: largest TC whose XG buffer (+state) fits in ws
    int TC = 1024;
    while (TC > 64 &&
           (size_t)TC * B_SZ * G_SZ * 4 + 2 * B_SZ * H_SZ * 4 > ws_size)
        TC >>= 1;

    float* XG      = (float*)d_ws;
    float* h_state = (float*)((char*)d_ws + (size_t)TC * B_SZ * G_SZ * 4);
    float* c_state = h_state + B_SZ * H_SZ;

    const int NCH = T_LEN / TC;
    for (int ch = 0; ch < NCH; ++ch) {
        const float* xch = x + (size_t)ch * TC * B_SZ * I_SZ;
        hipLaunchKernelGGL(xg_gemm, dim3(TC * B_SZ / 128, 2), dim3(256), 0,
                           stream, xch, W_ih_f, b_f, XG);
        hipLaunchKernelGGL(lstm_rec, dim3(B_SZ), dim3(256), 0, stream,
                           XG, W_hh_f, h_state, c_state, TC, ch == 0 ? 1 : 0);
    }

    const float* x_last = x + (size_t)(T_LEN - 1) * B_SZ * I_SZ;
    hipLaunchKernelGGL(lstm_tail, dim3(B_SZ), dim3(256), 0, stream,
                       x_last, W_ih_r, b_r, h_state,
                       fc1_w, fc1_b, fc2_w, fc2_b, fc3_w, fc3_b, out);
}